// Round 1
// baseline (1143.285 us; speedup 1.0000x reference)
//
#include <hip/hip_runtime.h>

#define NN 50000
#define NE 800000
#define D_NODE 64
#define D_ATTR 16
#define D_T 16
#define D_MSG 96      // 64 + 16 + 16
#define D_OUT 128

// ---------------------------------------------------------------------------
// Phase 1: scatter-add  agg[row[e], :] += concat(x[col[e]], edge_attr[e], edge_t[e])
// One thread per (edge, float4-chunk): 24 chunks of 4 floats = 96 floats/edge.
// Chunks 0..15 -> x[col] (16 float4), 16..19 -> edge_attr, 20..23 -> edge_t.
// ---------------------------------------------------------------------------
__global__ __launch_bounds__(256) void scatter_kernel(
    const float4* __restrict__ x4,     // NN x 16 float4
    const int*    __restrict__ row,    // NE
    const int*    __restrict__ col,    // NE
    const float4* __restrict__ ea4,    // NE x 4 float4
    const float4* __restrict__ et4,    // NE x 4 float4
    float*        __restrict__ agg)    // NN x 96 floats
{
    int t = blockIdx.x * blockDim.x + threadIdx.x;
    const int total = NE * 24;
    if (t >= total) return;
    int e = t / 24;
    int c = t - e * 24;

    float4 v;
    if (c < 16) {
        int s = col[e];
        v = x4[(size_t)s * 16 + c];
    } else if (c < 20) {
        v = ea4[(size_t)e * 4 + (c - 16)];
    } else {
        v = et4[(size_t)e * 4 + (c - 20)];
    }

    float* dst = agg + (size_t)row[e] * D_MSG + c * 4;
    unsafeAtomicAdd(dst + 0, v.x);
    unsafeAtomicAdd(dst + 1, v.y);
    unsafeAtomicAdd(dst + 2, v.z);
    unsafeAtomicAdd(dst + 3, v.w);
}

// ---------------------------------------------------------------------------
// Phase 2: out[n, o] = 0.5*(agg[n,:] @ Wm[:,o]) + (x[n,:] @ Wr[:,o]) + (0.5*bm[o]+br[o])
// Block = 512 threads = 4 groups of 128 (one thread per output column o).
// Wm (96x128) and Wr (64x128) staged in LDS (80 KB). Each group register-tiles
// 4 nodes so each LDS W-read feeds 4 FMAs; agg/x row reads are wave-uniform
// float4 broadcasts straight from global (L2-resident).
// ---------------------------------------------------------------------------
__global__ __launch_bounds__(512) void dense_kernel(
    const float* __restrict__ agg,   // NN x 96
    const float* __restrict__ x,     // NN x 64
    const float* __restrict__ Wm,    // 96 x 128
    const float* __restrict__ bm,    // 128
    const float* __restrict__ Wr,    // 64 x 128
    const float* __restrict__ br,    // 128
    float*       __restrict__ out)   // NN x 128
{
    __shared__ float sWm[D_MSG * D_OUT];    // 49152 B
    __shared__ float sWr[D_NODE * D_OUT];   // 32768 B
    for (int i = threadIdx.x; i < D_MSG * D_OUT; i += 512)  sWm[i] = Wm[i];
    for (int i = threadIdx.x; i < D_NODE * D_OUT; i += 512) sWr[i] = Wr[i];
    __syncthreads();

    const int o = threadIdx.x & 127;
    const int g = threadIdx.x >> 7;            // group 0..3
    const float bias = 0.5f * bm[o] + br[o];

    const int stride = gridDim.x * 4 * 4;      // blocks * groups * node-tile
    for (int n0 = (blockIdx.x * 4 + g) * 4; n0 < NN; n0 += stride) {
        // NN % 4 == 0, so the 4-node tile never has a tail.
        float accm0 = 0.f, accm1 = 0.f, accm2 = 0.f, accm3 = 0.f;
        float accr0 = 0.f, accr1 = 0.f, accr2 = 0.f, accr3 = 0.f;

        const float4* ar0 = (const float4*)(agg + (size_t)(n0 + 0) * D_MSG);
        const float4* ar1 = (const float4*)(agg + (size_t)(n0 + 1) * D_MSG);
        const float4* ar2 = (const float4*)(agg + (size_t)(n0 + 2) * D_MSG);
        const float4* ar3 = (const float4*)(agg + (size_t)(n0 + 3) * D_MSG);

#define STEP_M(k4, j, comp)                                   \
        {                                                     \
            float w = sWm[((k4) * 4 + (j)) * D_OUT + o];      \
            accm0 = fmaf(a0.comp, w, accm0);                  \
            accm1 = fmaf(a1.comp, w, accm1);                  \
            accm2 = fmaf(a2.comp, w, accm2);                  \
            accm3 = fmaf(a3.comp, w, accm3);                  \
        }
#pragma unroll 6
        for (int k4 = 0; k4 < D_MSG / 4; ++k4) {
            float4 a0 = ar0[k4], a1 = ar1[k4], a2 = ar2[k4], a3 = ar3[k4];
            STEP_M(k4, 0, x) STEP_M(k4, 1, y) STEP_M(k4, 2, z) STEP_M(k4, 3, w)
        }
#undef STEP_M

        const float4* xr0 = (const float4*)(x + (size_t)(n0 + 0) * D_NODE);
        const float4* xr1 = (const float4*)(x + (size_t)(n0 + 1) * D_NODE);
        const float4* xr2 = (const float4*)(x + (size_t)(n0 + 2) * D_NODE);
        const float4* xr3 = (const float4*)(x + (size_t)(n0 + 3) * D_NODE);

#define STEP_R(k4, j, comp)                                   \
        {                                                     \
            float w = sWr[((k4) * 4 + (j)) * D_OUT + o];      \
            accr0 = fmaf(a0.comp, w, accr0);                  \
            accr1 = fmaf(a1.comp, w, accr1);                  \
            accr2 = fmaf(a2.comp, w, accr2);                  \
            accr3 = fmaf(a3.comp, w, accr3);                  \
        }
#pragma unroll 4
        for (int k4 = 0; k4 < D_NODE / 4; ++k4) {
            float4 a0 = xr0[k4], a1 = xr1[k4], a2 = xr2[k4], a3 = xr3[k4];
            STEP_R(k4, 0, x) STEP_R(k4, 1, y) STEP_R(k4, 2, z) STEP_R(k4, 3, w)
        }
#undef STEP_R

        out[(size_t)(n0 + 0) * D_OUT + o] = 0.5f * accm0 + accr0 + bias;
        out[(size_t)(n0 + 1) * D_OUT + o] = 0.5f * accm1 + accr1 + bias;
        out[(size_t)(n0 + 2) * D_OUT + o] = 0.5f * accm2 + accr2 + bias;
        out[(size_t)(n0 + 3) * D_OUT + o] = 0.5f * accm3 + accr3 + bias;
    }
}

extern "C" void kernel_launch(void* const* d_in, const int* in_sizes, int n_in,
                              void* d_out, int out_size, void* d_ws, size_t ws_size,
                              hipStream_t stream) {
    const float* x  = (const float*)d_in[0];
    const int*   ei = (const int*)d_in[1];   // [2, NE]: row = ei[0:NE), col = ei[NE:2NE)
    const float* ea = (const float*)d_in[2];
    const float* et = (const float*)d_in[3];
    const float* Wm = (const float*)d_in[4];
    const float* bm = (const float*)d_in[5];
    const float* Wr = (const float*)d_in[6];
    const float* br = (const float*)d_in[7];
    float* out = (float*)d_out;
    float* agg = (float*)d_ws;               // NN x 96 floats = 19.2 MB

    hipMemsetAsync(agg, 0, (size_t)NN * D_MSG * sizeof(float), stream);

    const int total = NE * 24;
    scatter_kernel<<<(total + 255) / 256, 256, 0, stream>>>(
        (const float4*)x, ei, ei + NE,
        (const float4*)ea, (const float4*)et, agg);

    dense_kernel<<<256, 512, 0, stream>>>(agg, x, Wm, bm, Wr, br, out);
}

// Round 2
// 413.142 us; speedup vs baseline: 2.7673x; 2.7673x over previous
//
#include <hip/hip_runtime.h>

#define NN 50000
#define NE 800000
#define D_NODE 64
#define D_ATTR 16
#define D_T 16
#define D_MSG 96      // 64 + 16 + 16
#define D_OUT 128

// ---------------- ws layout (fast path) ----------------
// cnt : NN int                     @ 0
// off : NN int                     @ NN*4
// cur : NN int                     @ 2*NN*4
// perm: NE int2 (e, col[e])        @ 600000   (8B aligned)
// agg : NN*96 float                @ 7000000  (16B aligned)
#define CNT_OFF  0
#define OFF_OFF  (NN * 4)
#define CUR_OFF  (2 * NN * 4)
#define PERM_OFF 600000
#define AGG_OFF  7000000
#define WS_NEEDED (AGG_OFF + NN * D_MSG * 4)

// ---------------------------------------------------------------------------
// Step 1: per-row histogram
// ---------------------------------------------------------------------------
__global__ __launch_bounds__(256) void hist_kernel(
    const int* __restrict__ row, int* __restrict__ cnt)
{
    int e = blockIdx.x * blockDim.x + threadIdx.x;
    if (e < NE) atomicAdd(&cnt[row[e]], 1);
}

// ---------------------------------------------------------------------------
// Step 2: exclusive prefix scan of cnt -> off (and cur copy). Single block.
// ---------------------------------------------------------------------------
__global__ __launch_bounds__(1024) void scan_kernel(
    const int* __restrict__ cnt, int* __restrict__ off, int* __restrict__ cur)
{
    __shared__ int part[1024];
    const int t = threadIdx.x;
    const int per = (NN + 1023) / 1024;   // 49
    const int base = t * per;

    int s = 0;
    for (int i = 0; i < per; ++i) {
        int idx = base + i;
        if (idx < NN) s += cnt[idx];
    }
    part[t] = s;
    __syncthreads();
    // Hillis-Steele inclusive scan over the 1024 partials
    for (int d = 1; d < 1024; d <<= 1) {
        int v = (t >= d) ? part[t - d] : 0;
        __syncthreads();
        part[t] += v;
        __syncthreads();
    }
    int run = (t == 0) ? 0 : part[t - 1];
    for (int i = 0; i < per; ++i) {
        int idx = base + i;
        if (idx < NN) {
            off[idx] = run;
            cur[idx] = run;
            run += cnt[idx];
        }
    }
}

// ---------------------------------------------------------------------------
// Step 3: bucket edges into CSR slots; store (e, col[e]) so the gather's
// dependent-load chain is only 2 deep.
// ---------------------------------------------------------------------------
__global__ __launch_bounds__(256) void bucket_kernel(
    const int* __restrict__ row, const int* __restrict__ col,
    int* __restrict__ cur, int2* __restrict__ perm)
{
    int e = blockIdx.x * blockDim.x + threadIdx.x;
    if (e >= NE) return;
    int pos = atomicAdd(&cur[row[e]], 1);
    perm[pos] = make_int2(e, col[e]);
}

// ---------------------------------------------------------------------------
// Step 4: gather-aggregate. One wave64 per node.
//   lane l (0..63): acc0 = sum over edges of x[col*64 + l]          (256B coalesced)
//   lane l (0..31): acc1 = sum of ea[e*16+l] (l<16) / et[e*16+l-16] (2x64B coalesced)
// No atomics; agg fully overwritten (deg-0 nodes write zeros), so no memset.
// ---------------------------------------------------------------------------
__global__ __launch_bounds__(256) void gather_kernel(
    const float* __restrict__ x,    // NN x 64
    const float* __restrict__ ea,   // NE x 16
    const float* __restrict__ et,   // NE x 16
    const int*  __restrict__ off,
    const int*  __restrict__ cnt,
    const int2* __restrict__ perm,
    float* __restrict__ agg)        // NN x 96
{
    const int node = blockIdx.x * 4 + (threadIdx.x >> 6);
    const int lane = threadIdx.x & 63;
    if (node >= NN) return;

    const int beg = off[node];
    const int n   = cnt[node];

    // lane-fixed base for the ea/et half (lanes 0..31 only)
    const float* eb = (lane < 16) ? (ea + lane) : (et + (lane - 16));

    float acc0 = 0.f, acc1 = 0.f;
    int2 p0 = make_int2(0, 0);
    if (n > 0) p0 = perm[beg];
    for (int j = 0; j < n; ++j) {
        int2 p = p0;
        if (j + 1 < n) p0 = perm[beg + j + 1];   // prefetch next edge id
        acc0 += x[(size_t)p.y * D_NODE + lane];
        if (lane < 32) acc1 += eb[(size_t)p.x * 16];
    }

    float* dst = agg + (size_t)node * D_MSG;
    dst[lane] = acc0;
    if (lane < 32) dst[D_NODE + lane] = acc1;
}

// ---------------------------------------------------------------------------
// Fallback phase 1 (round-1 atomic scatter), used only if ws is too small.
// ---------------------------------------------------------------------------
__global__ __launch_bounds__(256) void scatter_kernel(
    const float4* __restrict__ x4,
    const int*    __restrict__ row,
    const int*    __restrict__ col,
    const float4* __restrict__ ea4,
    const float4* __restrict__ et4,
    float*        __restrict__ agg)
{
    int t = blockIdx.x * blockDim.x + threadIdx.x;
    const int total = NE * 24;
    if (t >= total) return;
    int e = t / 24;
    int c = t - e * 24;

    float4 v;
    if (c < 16) {
        int s = col[e];
        v = x4[(size_t)s * 16 + c];
    } else if (c < 20) {
        v = ea4[(size_t)e * 4 + (c - 16)];
    } else {
        v = et4[(size_t)e * 4 + (c - 20)];
    }

    float* dst = agg + (size_t)row[e] * D_MSG + c * 4;
    unsafeAtomicAdd(dst + 0, v.x);
    unsafeAtomicAdd(dst + 1, v.y);
    unsafeAtomicAdd(dst + 2, v.z);
    unsafeAtomicAdd(dst + 3, v.w);
}

// ---------------------------------------------------------------------------
// Phase 2: out[n,o] = 0.5*(agg[n,:]@Wm[:,o]) + (x[n,:]@Wr[:,o]) + (0.5*bm+br)
// 512 threads = 4 groups x 128 (thread = output col o); Wm+Wr in 80KB LDS;
// 4-node register tile per group.
// ---------------------------------------------------------------------------
__global__ __launch_bounds__(512) void dense_kernel(
    const float* __restrict__ agg,
    const float* __restrict__ x,
    const float* __restrict__ Wm,
    const float* __restrict__ bm,
    const float* __restrict__ Wr,
    const float* __restrict__ br,
    float*       __restrict__ out)
{
    __shared__ float sWm[D_MSG * D_OUT];
    __shared__ float sWr[D_NODE * D_OUT];
    for (int i = threadIdx.x; i < D_MSG * D_OUT; i += 512)  sWm[i] = Wm[i];
    for (int i = threadIdx.x; i < D_NODE * D_OUT; i += 512) sWr[i] = Wr[i];
    __syncthreads();

    const int o = threadIdx.x & 127;
    const int g = threadIdx.x >> 7;
    const float bias = 0.5f * bm[o] + br[o];

    const int stride = gridDim.x * 4 * 4;
    for (int n0 = (blockIdx.x * 4 + g) * 4; n0 < NN; n0 += stride) {
        float accm0 = 0.f, accm1 = 0.f, accm2 = 0.f, accm3 = 0.f;
        float accr0 = 0.f, accr1 = 0.f, accr2 = 0.f, accr3 = 0.f;

        const float4* ar0 = (const float4*)(agg + (size_t)(n0 + 0) * D_MSG);
        const float4* ar1 = (const float4*)(agg + (size_t)(n0 + 1) * D_MSG);
        const float4* ar2 = (const float4*)(agg + (size_t)(n0 + 2) * D_MSG);
        const float4* ar3 = (const float4*)(agg + (size_t)(n0 + 3) * D_MSG);

#define STEP_M(k4, j, comp)                                   \
        {                                                     \
            float w = sWm[((k4) * 4 + (j)) * D_OUT + o];      \
            accm0 = fmaf(a0.comp, w, accm0);                  \
            accm1 = fmaf(a1.comp, w, accm1);                  \
            accm2 = fmaf(a2.comp, w, accm2);                  \
            accm3 = fmaf(a3.comp, w, accm3);                  \
        }
#pragma unroll 6
        for (int k4 = 0; k4 < D_MSG / 4; ++k4) {
            float4 a0 = ar0[k4], a1 = ar1[k4], a2 = ar2[k4], a3 = ar3[k4];
            STEP_M(k4, 0, x) STEP_M(k4, 1, y) STEP_M(k4, 2, z) STEP_M(k4, 3, w)
        }
#undef STEP_M

        const float4* xr0 = (const float4*)(x + (size_t)(n0 + 0) * D_NODE);
        const float4* xr1 = (const float4*)(x + (size_t)(n0 + 1) * D_NODE);
        const float4* xr2 = (const float4*)(x + (size_t)(n0 + 2) * D_NODE);
        const float4* xr3 = (const float4*)(x + (size_t)(n0 + 3) * D_NODE);

#define STEP_R(k4, j, comp)                                   \
        {                                                     \
            float w = sWr[((k4) * 4 + (j)) * D_OUT + o];      \
            accr0 = fmaf(a0.comp, w, accr0);                  \
            accr1 = fmaf(a1.comp, w, accr1);                  \
            accr2 = fmaf(a2.comp, w, accr2);                  \
            accr3 = fmaf(a3.comp, w, accr3);                  \
        }
#pragma unroll 4
        for (int k4 = 0; k4 < D_NODE / 4; ++k4) {
            float4 a0 = xr0[k4], a1 = xr1[k4], a2 = xr2[k4], a3 = xr3[k4];
            STEP_R(k4, 0, x) STEP_R(k4, 1, y) STEP_R(k4, 2, z) STEP_R(k4, 3, w)
        }
#undef STEP_R

        out[(size_t)(n0 + 0) * D_OUT + o] = 0.5f * accm0 + accr0 + bias;
        out[(size_t)(n0 + 1) * D_OUT + o] = 0.5f * accm1 + accr1 + bias;
        out[(size_t)(n0 + 2) * D_OUT + o] = 0.5f * accm2 + accr2 + bias;
        out[(size_t)(n0 + 3) * D_OUT + o] = 0.5f * accm3 + accr3 + bias;
    }
}

extern "C" void kernel_launch(void* const* d_in, const int* in_sizes, int n_in,
                              void* d_out, int out_size, void* d_ws, size_t ws_size,
                              hipStream_t stream) {
    const float* x  = (const float*)d_in[0];
    const int*   ei = (const int*)d_in[1];   // row = ei[0:NE), col = ei[NE:2NE)
    const float* ea = (const float*)d_in[2];
    const float* et = (const float*)d_in[3];
    const float* Wm = (const float*)d_in[4];
    const float* bm = (const float*)d_in[5];
    const float* Wr = (const float*)d_in[6];
    const float* br = (const float*)d_in[7];
    float* out = (float*)d_out;
    const int* row = ei;
    const int* col = ei + NE;

    char* ws = (char*)d_ws;

    if (ws_size >= (size_t)WS_NEEDED) {
        int*  cnt  = (int*)(ws + CNT_OFF);
        int*  off  = (int*)(ws + OFF_OFF);
        int*  cur  = (int*)(ws + CUR_OFF);
        int2* perm = (int2*)(ws + PERM_OFF);
        float* agg = (float*)(ws + AGG_OFF);

        hipMemsetAsync(cnt, 0, NN * sizeof(int), stream);
        hist_kernel<<<(NE + 255) / 256, 256, 0, stream>>>(row, cnt);
        scan_kernel<<<1, 1024, 0, stream>>>(cnt, off, cur);
        bucket_kernel<<<(NE + 255) / 256, 256, 0, stream>>>(row, col, cur, perm);
        gather_kernel<<<(NN + 3) / 4, 256, 0, stream>>>(x, ea, et, off, cnt, perm, agg);
        dense_kernel<<<256, 512, 0, stream>>>(agg, x, Wm, bm, Wr, br, out);
    } else {
        float* agg = (float*)d_ws;
        hipMemsetAsync(agg, 0, (size_t)NN * D_MSG * sizeof(float), stream);
        const int total = NE * 24;
        scatter_kernel<<<(total + 255) / 256, 256, 0, stream>>>(
            (const float4*)x, row, col, (const float4*)ea, (const float4*)et, agg);
        dense_kernel<<<256, 512, 0, stream>>>(agg, x, Wm, bm, Wr, br, out);
    }
}